// Round 9
// baseline (1316.429 us; speedup 1.0000x reference)
//
#include <hip/hip_runtime.h>

typedef unsigned short ushort_t;
typedef __bf16 bf16x8 __attribute__((ext_vector_type(8)));
typedef __bf16 bf16x2 __attribute__((ext_vector_type(2)));
typedef float f32x4 __attribute__((ext_vector_type(4)));

#define LOG2E 1.4426950408889634f
#define LN2   0.6931471805599453f

__device__ __forceinline__ ushort_t f2bf(float f) {
    unsigned u;
    __builtin_memcpy(&u, &f, 4);
    u += 0x7fffu + ((u >> 16) & 1u);   // RNE
    return (ushort_t)(u >> 16);
}

// inputs pre-scaled by log2(e): silu2(y) = y * sigmoid2(y) = log2e*silu(x).
// Downstream weights carry the compensating ln2. Simple form (one rcp per
// silu): R4 proved the quad-batched rcp variant net-regresses.
__device__ __forceinline__ float silu2(float y) {
    float e = __builtin_amdgcn_exp2f(-y);
    return y * __builtin_amdgcn_rcpf(1.0f + e);
}

__device__ __forceinline__ float rdlane(float v, int l) {
    return __builtin_bit_cast(float, __builtin_amdgcn_readlane(__builtin_bit_cast(int, v), l));
}

// XOR-swizzled A-fragment LDS layout for 16x16x32 bf16 MFMA (verified):
// element (row,k) -> frag  = (k>>5)   [within a wave's 16-row region]
//                    slot  = ((row&15) ^ ((k>>5)&3) ^ (((k>>3)&3)<<2))
//                            + 16*((k>>3)&3)                             [16 B]
//                    byte  = (k&7)*2
// Reads: b128, 64 distinct slots, conflict-free. Writes: 2-way (free).
//
// STRUCTURE LOCKED TO THE R1 SHAPE (proven spill-free at VGPR=84):
// ks-outer GEMM, A=H0 frags cached in regs, B=W1 frag read+consumed,
// acc[2][8] used ONLY as MFMA C-chain, epilogue strictly after the GEMM.
// R5/R6/R7 swapped-operand / fused-epilogue / 32x32 variants ALL spilled
// (1.7-3.9 GB scratch FETCH). DO NOT revisit that family.
//
// R9 change: W1 frags come from GLOBAL (workspace, pre-converted to bf16
// frag layout by prep_w1). W1 is 32 KB read-only shared chip-wide ->
// L1 (32 KB/CU) / L2 resident; demand ~38 GB/s/CU << L1 BW. This frees
// 32 KB LDS: block LDS = sH0 16 KB only -> occupancy now VGPR-capped at
// 4 blocks/CU = 16 waves/CU (was 12). R8 showed no pipe saturated
// (VALU 62%, MFMA 14%, trans ~25%, DS ~40%) -> latency floor; more
// resident waves is the lever. Also: zero __syncthreads in this kernel.
//
// __launch_bounds__(256,4): 2nd arg = min BLOCKS/CU on this toolchain
// (R3 evidence) -> VGPR cap 128. Spill canary: FETCH_SIZE >~100 MB.

// Packed scatter accumulator: one f64 atomic carries sum + 65536*count.
#define CNT_UNIT 65536.0

// ---- prologue: W1 f32 -> bf16 frag layout in workspace (runs once) ----
__global__ void prep_w1(const float* __restrict__ W1, ushort_t* __restrict__ gW1)
{
    int tid = threadIdx.x;                 // one 256-thread block
    int n = tid >> 1, half = tid & 1;
    const float* src = W1 + n * 128;
#pragma unroll
    for (int dk = 0; dk < 8; dk++) {
        int k0   = half * 64 + dk * 8;
        int frag = (n >> 4) * 4 + (k0 >> 5);
        int slot = (n & 15) + 16 * ((k0 >> 3) & 3);
        ushort_t tmp[8];
#pragma unroll
        for (int t = 0; t < 8; t++) tmp[t] = f2bf(src[k0 + t]);
        *(uint4*)(&gW1[frag * 512 + slot * 8]) = *(const uint4*)tmp;
    }
}

__global__ __launch_bounds__(256, 4) void mlp_kernel(
    const float* __restrict__ v,    // [N,3] f32
    const float* __restrict__ rij,  // [E,3] f32
    const float* __restrict__ W0,   // [128,4]
    const float* __restrict__ b0,   // [128]
    const ushort_t* __restrict__ gW1, // [16384] bf16 frag layout (workspace)
    const float* __restrict__ b1,   // [128]
    const float* __restrict__ W2,   // [128]
    const float* __restrict__ b2,   // [1]
    const int* __restrict__ eidx,   // [2,E] int32
    double* __restrict__ acc_i, double* __restrict__ acc_j,
    int E, int nchunks)             // chunk = 64 edges (4 waves x 16)
{
    __shared__ ushort_t sH0[8192];   // 16 KB, XOR-swizzled; wave w owns frags [4w,4w+4)

    const int tid  = threadIdx.x;
    const int lane = tid & 63;
    const int wave = tid >> 6;

    // ---- per-lane constants (log2e folded) ----
    float4 w0q[2]; float b0v[2];
#pragma unroll
    for (int kk = 0; kk < 2; kk++) {
        int h = 2 * lane + kk;
        w0q[kk].x = W0[h * 4 + 0] * LOG2E;
        w0q[kk].y = W0[h * 4 + 1] * LOG2E;
        w0q[kk].z = W0[h * 4 + 2] * LOG2E;
        w0q[kk].w = W0[h * 4 + 3] * LOG2E;
        b0v[kk]   = b0[h] * LOG2E;
    }
    float b1v[8], w2v[8];
#pragma unroll
    for (int nt = 0; nt < 8; nt++) {
        int ccol = nt * 16 + (lane & 15);
        b1v[nt] = b1[ccol] * LOG2E;   // pre-activation scale for layer-1 silu2
        w2v[nt] = W2[ccol] * LN2;     // compensates log2e in silu2 output
    }
    const float b2f = b2[0];
    // per-lane W1-frag base (16 B per lane within each 1 KB fragment)
    const ushort_t* gW1l = gW1 + lane * 8;

    const int q = lane >> 4, c = lane & 15, p = (lane >> 2) & 3, bsub = lane & 3;
    const int ple  = lane >> 2;     // edge-in-wave this lane preloads
    const int comp = lane & 3;      // 0..2: v component, 3: |r|/H

    // ---- gather preload for one chunk (lane-parallel) ----
    auto preload = [&](int ch, float& val_o, int& idx_o) {
        float val = 0.f; int idxr = 0;
        int pe = ch * 64 + wave * 16 + ple;
        if (ch < nchunks && pe < E) {
            if (comp == 3) {
                float r0 = rij[3 * pe], r1 = rij[3 * pe + 1], r2 = rij[3 * pe + 2];
                val = sqrtf(fmaf(r0, r0, fmaf(r1, r1, r2 * r2))) * (1.0f / 3.0f);
            } else {
                int i = eidx[pe], jj = eidx[E + pe];
                idxr = (comp == 1) ? jj : i;
                val = v[3 * i + comp] - v[3 * jj + comp];
            }
        }
        val_o = val; idx_o = idxr;
    };

    float val; int idxr;
    preload(blockIdx.x, val, idxr);   // prologue load for first chunk

    for (int chunk = blockIdx.x; chunk < nchunks; chunk += gridDim.x) {
        const float val_cur = val;
        const int   idx_cur = idxr;
        // issue next chunk's gathers now; consumed one full iteration later
        preload(chunk + (int)gridDim.x, val, idxr);

        const int ebase = chunk * 64 + wave * 16;

        // ===== two temporal halves: layer0 -> 16-row LDS region -> H0 frags =====
        bf16x8 afr[2][4];
#pragma unroll
        for (int half = 0; half < 2; ++half) {
#pragma unroll
            for (int le = 0; le < 8; le++) {
                int se = half * 8 + le;
                float vx = rdlane(val_cur, se * 4 + 0);
                float vy = rdlane(val_cur, se * 4 + 1);
                float vz = rdlane(val_cur, se * 4 + 2);
                float rr = rdlane(val_cur, se * 4 + 3);
                float cc0 = fmaf(w0q[0].x, rr, b0v[0]);
                float dd0 = fmaf(w0q[0].y, vx, fmaf(w0q[0].z, vy, w0q[0].w * vz));
                float cc1 = fmaf(w0q[1].x, rr, b0v[1]);
                float dd1 = fmaf(w0q[1].y, vx, fmaf(w0q[1].z, vy, w0q[1].w * vz));
                float s0 = silu2(cc0 + dd0);   // x_i, h=2l
                float s1 = silu2(cc0 - dd0);   // x_j, h=2l
                float s2 = silu2(cc1 + dd1);   // x_i, h=2l+1
                float s3 = silu2(cc1 - dd1);   // x_j, h=2l+1
                bf16x2 pki, pkj;
                pki[0] = (__bf16)s0; pki[1] = (__bf16)s2;
                pkj[0] = (__bf16)s1; pkj[1] = (__bf16)s3;
                int mi = 2 * le;                  // x_i row in [0,16); x_j row = mi+1
                int fr = wave * 4 + q;
                int sli = ((mi ^ q ^ (p << 2)) & 15) + (p << 4);
                int slj = (((mi + 1) ^ q ^ (p << 2)) & 15) + (p << 4);
                ((unsigned*)sH0)[fr * 256 + sli * 4 + bsub] = __builtin_bit_cast(unsigned, pki);
                ((unsigned*)sH0)[fr * 256 + slj * 4 + bsub] = __builtin_bit_cast(unsigned, pkj);
            }
            // cache this half's H0 fragments before half 1 overwrites the region
#pragma unroll
            for (int ks = 0; ks < 4; ks++) {
                int sl_rd = (((lane & 15) ^ ks ^ (q << 2)) & 15) + 16 * q;
                afr[half][ks] = *(const bf16x8*)(&sH0[(wave * 4 + ks) * 512 + sl_rd * 8]);
            }
        }

        // ===== GEMM: h1_pre' = H0' @ W1^T + b1' (R1 shape; B from global) =====
        f32x4 acc[2][8];
#pragma unroll
        for (int t = 0; t < 2; t++)
#pragma unroll
            for (int nt = 0; nt < 8; nt++)
                acc[t][nt] = (f32x4){b1v[nt], b1v[nt], b1v[nt], b1v[nt]};

#pragma unroll
        for (int ks = 0; ks < 4; ks++) {
#pragma unroll
            for (int nt = 0; nt < 8; nt++) {
                bf16x8 bb = *(const bf16x8*)(&gW1l[(nt * 4 + ks) * 512]);
                acc[0][nt] = __builtin_amdgcn_mfma_f32_16x16x32_bf16(afr[0][ks], bb, acc[0][nt], 0, 0, 0);
                acc[1][nt] = __builtin_amdgcn_mfma_f32_16x16x32_bf16(afr[1][ks], bb, acc[1][nt], 0, 0, 0);
            }
        }

        // ===== epilogue: silu2(h1') . (W2*ln2) -> +b2 -> packed f64 scatter-add =====
        float rs[2][4] = {{0.f, 0.f, 0.f, 0.f}, {0.f, 0.f, 0.f, 0.f}};
#pragma unroll
        for (int t = 0; t < 2; t++)
#pragma unroll
            for (int nt = 0; nt < 8; nt++)
#pragma unroll
                for (int r = 0; r < 4; r++) {
                    float x = acc[t][nt][r];          // b1' folded into acc init
                    rs[t][r] = fmaf(silu2(x), w2v[nt], rs[t][r]);
                }
#pragma unroll
        for (int t = 0; t < 2; t++)
#pragma unroll
            for (int r = 0; r < 4; r++) {
                float s = rs[t][r];
                s += __shfl_xor(s, 1, 64);
                s += __shfl_xor(s, 2, 64);
                s += __shfl_xor(s, 4, 64);
                s += __shfl_xor(s, 8, 64);
                int el  = t * 8 + q * 2 + (r >> 1);        // edge within wave's 16
                int src = el * 4 + (r & 1);                // comp0 lane holds i, comp1 holds j
                int node = __shfl(idx_cur, src, 64);
                int e = ebase + el;
                if (c == 0 && e < E) {
                    double contrib = (double)(s + b2f) + CNT_UNIT;
                    if (r & 1) atomicAdd(&acc_j[node], contrib);
                    else       atomicAdd(&acc_i[node], contrib);
                }
            }
        // wave-local LDS WAR across chunks is safe: one wave's DS ops are in-order.
    }
}

__global__ void finalize_kernel(const double* __restrict__ acc_i,
                                const double* __restrict__ acc_j,
                                float* __restrict__ out, int N)
{
    int n = blockIdx.x * 256 + threadIdx.x;
    if (n < N) {
        double ti = acc_i[n], tj = acc_j[n];
        double ci = rint(ti * (1.0 / CNT_UNIT));
        double cj = rint(tj * (1.0 / CNT_UNIT));
        double si = ti - ci * CNT_UNIT;
        double sj = tj - cj * CNT_UNIT;
        out[n] = (float)(si / fmax(ci, 1.0) + sj / fmax(cj, 1.0));
    }
}

extern "C" void kernel_launch(void* const* d_in, const int* in_sizes, int n_in,
                              void* d_out, int out_size, void* d_ws, size_t ws_size,
                              hipStream_t stream) {
    const float* v   = (const float*)d_in[0];
    const float* rij = (const float*)d_in[1];
    const float* W0  = (const float*)d_in[2];
    const float* b0  = (const float*)d_in[3];
    const float* W1  = (const float*)d_in[4];
    const float* b1  = (const float*)d_in[5];
    const float* W2  = (const float*)d_in[6];
    const float* b2  = (const float*)d_in[7];
    const int* eidx  = (const int*)d_in[8];

    const int E = in_sizes[1] / 3;
    const int N = out_size;

    double* acc_i = (double*)d_ws;
    double* acc_j = acc_i + N;
    ushort_t* gW1 = (ushort_t*)(acc_j + N);   // 32 KB, 16B-aligned (16N offset)

    hipMemsetAsync(d_ws, 0, (size_t)2 * N * sizeof(double), stream);

    prep_w1<<<1, 256, 0, stream>>>(W1, gW1);

    int nchunks = (E + 63) / 64;
    int grid = nchunks < 1024 ? nchunks : 1024;   // 4 blocks/CU resident
    mlp_kernel<<<grid, 256, 0, stream>>>(v, rij, W0, b0, gW1, b1, W2, b2, eidx,
                                         acc_i, acc_j, E, nchunks);
    finalize_kernel<<<(N + 255) / 256, 256, 0, stream>>>(acc_i, acc_j,
                                                         (float*)d_out, N);
}

// Round 10
// 475.807 us; speedup vs baseline: 2.7667x; 2.7667x over previous
//
#include <hip/hip_runtime.h>

typedef unsigned short ushort_t;
typedef __bf16 bf16x8 __attribute__((ext_vector_type(8)));
typedef __bf16 bf16x2 __attribute__((ext_vector_type(2)));
typedef float f32x4 __attribute__((ext_vector_type(4)));

#define LOG2E 1.4426950408889634f
#define LN2   0.6931471805599453f

__device__ __forceinline__ ushort_t f2bf(float f) {
    unsigned u;
    __builtin_memcpy(&u, &f, 4);
    u += 0x7fffu + ((u >> 16) & 1u);   // RNE
    return (ushort_t)(u >> 16);
}

// inputs pre-scaled by log2(e): silu2(y) = y * sigmoid2(y) = log2e*silu(x).
// Downstream weights carry the compensating ln2. Simple form (one rcp per
// silu): R4 proved the quad-batched rcp variant net-regresses.
__device__ __forceinline__ float silu2(float y) {
    float e = __builtin_amdgcn_exp2f(-y);
    return y * __builtin_amdgcn_rcpf(1.0f + e);
}

__device__ __forceinline__ float rdlane(float v, int l) {
    return __builtin_bit_cast(float, __builtin_amdgcn_readlane(__builtin_bit_cast(int, v), l));
}

// ====================== LAUNCH-BOUNDS LAW (measured) ======================
// On this toolchain, __launch_bounds__(B, arg2) caps VGPR at 256/arg2,
// INDEPENDENT of block size B:
//   arg2=4 -> cap 64  (R3: 512-thr, R9: 256-thr; both spilled GBs)
//   arg2=3 -> cap ~85 (R1 allocated exactly 84)
//   arg2=2 -> cap 128 (R7 allocated exactly 128; R4's 120 fit)
// This retro-explains the R5-R7 "spill family": live sets of ~120-150
// regs under caps 85/85/128. Spill canary: FETCH_SIZE >> 100 MB with
// read:write >> 2:1. USE (256,2) unless live set provably < 85.
// =========================================================================
//
// XOR-swizzled A-fragment LDS layout for 16x16x32 bf16 MFMA (verified):
// element (row,k) -> frag  = (k>>5)   [within a wave's 16-row region]
//                    slot  = ((row&15) ^ ((k>>5)&3) ^ (((k>>3)&3)<<2))
//                            + 16*((k>>3)&3)                             [16 B]
//                    byte  = (k&7)*2
// Reads: b128, 64 distinct slots, conflict-free. Writes: 2-way (free).
//
// STRUCTURE: R1 shape (ks-outer GEMM, A=H0 frags in regs, B=W1 frag
// read+consumed, acc[2][8] as MFMA C-chain only, epilogue strictly after).
//
// R10 = R9 design, cap fixed: W1 frags from GLOBAL workspace (prep_w1
// pre-converts to bf16 frag layout once). W1 is 32 KB read-only shared
// chip-wide -> L1/L2-resident; FETCH (HBM-only) unaffected. Block LDS =
// sH0 16 KB only -> LDS allows 10 blocks/CU; with VGPR <= 128 occupancy
// becomes 4 waves/SIMD = 16 waves/CU (was 12). R8 showed no pipe
// saturated (VALU 62%, MFMA 14%, trans ~25%, DS ~40%) -> latency floor;
// resident-wave count is the lever under test. Zero __syncthreads.

// Packed scatter accumulator: one f64 atomic carries sum + 65536*count.
#define CNT_UNIT 65536.0

// ---- prologue: W1 f32 -> bf16 frag layout in workspace (runs once) ----
__global__ void prep_w1(const float* __restrict__ W1, ushort_t* __restrict__ gW1)
{
    int tid = threadIdx.x;                 // one 256-thread block
    int n = tid >> 1, half = tid & 1;
    const float* src = W1 + n * 128;
#pragma unroll
    for (int dk = 0; dk < 8; dk++) {
        int k0   = half * 64 + dk * 8;
        int frag = (n >> 4) * 4 + (k0 >> 5);
        int slot = (n & 15) + 16 * ((k0 >> 3) & 3);
        ushort_t tmp[8];
#pragma unroll
        for (int t = 0; t < 8; t++) tmp[t] = f2bf(src[k0 + t]);
        *(uint4*)(&gW1[frag * 512 + slot * 8]) = *(const uint4*)tmp;
    }
}

__global__ __launch_bounds__(256, 2) void mlp_kernel(
    const float* __restrict__ v,    // [N,3] f32
    const float* __restrict__ rij,  // [E,3] f32
    const float* __restrict__ W0,   // [128,4]
    const float* __restrict__ b0,   // [128]
    const ushort_t* __restrict__ gW1, // [16384] bf16 frag layout (workspace)
    const float* __restrict__ b1,   // [128]
    const float* __restrict__ W2,   // [128]
    const float* __restrict__ b2,   // [1]
    const int* __restrict__ eidx,   // [2,E] int32
    double* __restrict__ acc_i, double* __restrict__ acc_j,
    int E, int nchunks)             // chunk = 64 edges (4 waves x 16)
{
    __shared__ ushort_t sH0[8192];   // 16 KB, XOR-swizzled; wave w owns frags [4w,4w+4)

    const int tid  = threadIdx.x;
    const int lane = tid & 63;
    const int wave = tid >> 6;

    // ---- per-lane constants (log2e folded) ----
    float4 w0q[2]; float b0v[2];
#pragma unroll
    for (int kk = 0; kk < 2; kk++) {
        int h = 2 * lane + kk;
        w0q[kk].x = W0[h * 4 + 0] * LOG2E;
        w0q[kk].y = W0[h * 4 + 1] * LOG2E;
        w0q[kk].z = W0[h * 4 + 2] * LOG2E;
        w0q[kk].w = W0[h * 4 + 3] * LOG2E;
        b0v[kk]   = b0[h] * LOG2E;
    }
    float b1v[8], w2v[8];
#pragma unroll
    for (int nt = 0; nt < 8; nt++) {
        int ccol = nt * 16 + (lane & 15);
        b1v[nt] = b1[ccol] * LOG2E;   // pre-activation scale for layer-1 silu2
        w2v[nt] = W2[ccol] * LN2;     // compensates log2e in silu2 output
    }
    const float b2f = b2[0];
    // per-lane W1-frag base (16 B per lane within each 1 KB fragment)
    const ushort_t* gW1l = gW1 + lane * 8;

    const int q = lane >> 4, c = lane & 15, p = (lane >> 2) & 3, bsub = lane & 3;
    const int ple  = lane >> 2;     // edge-in-wave this lane preloads
    const int comp = lane & 3;      // 0..2: v component, 3: |r|/H

    // ---- gather preload for one chunk (lane-parallel) ----
    auto preload = [&](int ch, float& val_o, int& idx_o) {
        float val = 0.f; int idxr = 0;
        int pe = ch * 64 + wave * 16 + ple;
        if (ch < nchunks && pe < E) {
            if (comp == 3) {
                float r0 = rij[3 * pe], r1 = rij[3 * pe + 1], r2 = rij[3 * pe + 2];
                val = sqrtf(fmaf(r0, r0, fmaf(r1, r1, r2 * r2))) * (1.0f / 3.0f);
            } else {
                int i = eidx[pe], jj = eidx[E + pe];
                idxr = (comp == 1) ? jj : i;
                val = v[3 * i + comp] - v[3 * jj + comp];
            }
        }
        val_o = val; idx_o = idxr;
    };

    float val; int idxr;
    preload(blockIdx.x, val, idxr);   // prologue load for first chunk

    for (int chunk = blockIdx.x; chunk < nchunks; chunk += gridDim.x) {
        const float val_cur = val;
        const int   idx_cur = idxr;
        // issue next chunk's gathers now; consumed one full iteration later
        preload(chunk + (int)gridDim.x, val, idxr);

        const int ebase = chunk * 64 + wave * 16;

        // ===== two temporal halves: layer0 -> 16-row LDS region -> H0 frags =====
        bf16x8 afr[2][4];
#pragma unroll
        for (int half = 0; half < 2; ++half) {
#pragma unroll
            for (int le = 0; le < 8; le++) {
                int se = half * 8 + le;
                float vx = rdlane(val_cur, se * 4 + 0);
                float vy = rdlane(val_cur, se * 4 + 1);
                float vz = rdlane(val_cur, se * 4 + 2);
                float rr = rdlane(val_cur, se * 4 + 3);
                float cc0 = fmaf(w0q[0].x, rr, b0v[0]);
                float dd0 = fmaf(w0q[0].y, vx, fmaf(w0q[0].z, vy, w0q[0].w * vz));
                float cc1 = fmaf(w0q[1].x, rr, b0v[1]);
                float dd1 = fmaf(w0q[1].y, vx, fmaf(w0q[1].z, vy, w0q[1].w * vz));
                float s0 = silu2(cc0 + dd0);   // x_i, h=2l
                float s1 = silu2(cc0 - dd0);   // x_j, h=2l
                float s2 = silu2(cc1 + dd1);   // x_i, h=2l+1
                float s3 = silu2(cc1 - dd1);   // x_j, h=2l+1
                bf16x2 pki, pkj;
                pki[0] = (__bf16)s0; pki[1] = (__bf16)s2;
                pkj[0] = (__bf16)s1; pkj[1] = (__bf16)s3;
                int mi = 2 * le;                  // x_i row in [0,16); x_j row = mi+1
                int fr = wave * 4 + q;
                int sli = ((mi ^ q ^ (p << 2)) & 15) + (p << 4);
                int slj = (((mi + 1) ^ q ^ (p << 2)) & 15) + (p << 4);
                ((unsigned*)sH0)[fr * 256 + sli * 4 + bsub] = __builtin_bit_cast(unsigned, pki);
                ((unsigned*)sH0)[fr * 256 + slj * 4 + bsub] = __builtin_bit_cast(unsigned, pkj);
            }
            // cache this half's H0 fragments before half 1 overwrites the region
#pragma unroll
            for (int ks = 0; ks < 4; ks++) {
                int sl_rd = (((lane & 15) ^ ks ^ (q << 2)) & 15) + 16 * q;
                afr[half][ks] = *(const bf16x8*)(&sH0[(wave * 4 + ks) * 512 + sl_rd * 8]);
            }
        }

        // ===== GEMM: h1_pre' = H0' @ W1^T + b1' (R1 shape; B from global) =====
        f32x4 acc[2][8];
#pragma unroll
        for (int t = 0; t < 2; t++)
#pragma unroll
            for (int nt = 0; nt < 8; nt++)
                acc[t][nt] = (f32x4){b1v[nt], b1v[nt], b1v[nt], b1v[nt]};

#pragma unroll
        for (int ks = 0; ks < 4; ks++) {
#pragma unroll
            for (int nt = 0; nt < 8; nt++) {
                bf16x8 bb = *(const bf16x8*)(&gW1l[(nt * 4 + ks) * 512]);
                acc[0][nt] = __builtin_amdgcn_mfma_f32_16x16x32_bf16(afr[0][ks], bb, acc[0][nt], 0, 0, 0);
                acc[1][nt] = __builtin_amdgcn_mfma_f32_16x16x32_bf16(afr[1][ks], bb, acc[1][nt], 0, 0, 0);
            }
        }

        // ===== epilogue: silu2(h1') . (W2*ln2) -> +b2 -> packed f64 scatter-add =====
        float rs[2][4] = {{0.f, 0.f, 0.f, 0.f}, {0.f, 0.f, 0.f, 0.f}};
#pragma unroll
        for (int t = 0; t < 2; t++)
#pragma unroll
            for (int nt = 0; nt < 8; nt++)
#pragma unroll
                for (int r = 0; r < 4; r++) {
                    float x = acc[t][nt][r];          // b1' folded into acc init
                    rs[t][r] = fmaf(silu2(x), w2v[nt], rs[t][r]);
                }
#pragma unroll
        for (int t = 0; t < 2; t++)
#pragma unroll
            for (int r = 0; r < 4; r++) {
                float s = rs[t][r];
                s += __shfl_xor(s, 1, 64);
                s += __shfl_xor(s, 2, 64);
                s += __shfl_xor(s, 4, 64);
                s += __shfl_xor(s, 8, 64);
                int el  = t * 8 + q * 2 + (r >> 1);        // edge within wave's 16
                int src = el * 4 + (r & 1);                // comp0 lane holds i, comp1 holds j
                int node = __shfl(idx_cur, src, 64);
                int e = ebase + el;
                if (c == 0 && e < E) {
                    double contrib = (double)(s + b2f) + CNT_UNIT;
                    if (r & 1) atomicAdd(&acc_j[node], contrib);
                    else       atomicAdd(&acc_i[node], contrib);
                }
            }
        // wave-local LDS WAR across chunks is safe: one wave's DS ops are in-order.
    }
}

__global__ void finalize_kernel(const double* __restrict__ acc_i,
                                const double* __restrict__ acc_j,
                                float* __restrict__ out, int N)
{
    int n = blockIdx.x * 256 + threadIdx.x;
    if (n < N) {
        double ti = acc_i[n], tj = acc_j[n];
        double ci = rint(ti * (1.0 / CNT_UNIT));
        double cj = rint(tj * (1.0 / CNT_UNIT));
        double si = ti - ci * CNT_UNIT;
        double sj = tj - cj * CNT_UNIT;
        out[n] = (float)(si / fmax(ci, 1.0) + sj / fmax(cj, 1.0));
    }
}

extern "C" void kernel_launch(void* const* d_in, const int* in_sizes, int n_in,
                              void* d_out, int out_size, void* d_ws, size_t ws_size,
                              hipStream_t stream) {
    const float* v   = (const float*)d_in[0];
    const float* rij = (const float*)d_in[1];
    const float* W0  = (const float*)d_in[2];
    const float* b0  = (const float*)d_in[3];
    const float* W1  = (const float*)d_in[4];
    const float* b1  = (const float*)d_in[5];
    const float* W2  = (const float*)d_in[6];
    const float* b2  = (const float*)d_in[7];
    const int* eidx  = (const int*)d_in[8];

    const int E = in_sizes[1] / 3;
    const int N = out_size;

    double* acc_i = (double*)d_ws;
    double* acc_j = acc_i + N;
    ushort_t* gW1 = (ushort_t*)(acc_j + N);   // 32 KB, 16B-aligned (16N offset)

    hipMemsetAsync(d_ws, 0, (size_t)2 * N * sizeof(double), stream);

    prep_w1<<<1, 256, 0, stream>>>(W1, gW1);

    int nchunks = (E + 63) / 64;
    int grid = nchunks < 1024 ? nchunks : 1024;   // up to 4 blocks/CU resident
    mlp_kernel<<<grid, 256, 0, stream>>>(v, rij, W0, b0, gW1, b1, W2, b2, eidx,
                                         acc_i, acc_j, E, nchunks);
    finalize_kernel<<<(N + 255) / 256, 256, 0, stream>>>(acc_i, acc_j,
                                                         (float*)d_out, N);
}

// Round 11
// 408.992 us; speedup vs baseline: 3.2187x; 1.1634x over previous
//
#include <hip/hip_runtime.h>

typedef unsigned short ushort_t;
typedef __bf16 bf16x8 __attribute__((ext_vector_type(8)));
typedef __bf16 bf16x2 __attribute__((ext_vector_type(2)));
typedef float f32x2 __attribute__((ext_vector_type(2)));
typedef float f32x4 __attribute__((ext_vector_type(4)));

#define LOG2E 1.4426950408889634f
#define LN2   0.6931471805599453f

__device__ __forceinline__ ushort_t f2bf(float f) {
    unsigned u;
    __builtin_memcpy(&u, &f, 4);
    u += 0x7fffu + ((u >> 16) & 1u);   // RNE
    return (ushort_t)(u >> 16);
}

// ====================== LAUNCH-BOUNDS LAW (measured) ======================
// __launch_bounds__(B, arg2) caps VGPR at 256/arg2, independent of B:
//   arg2=4 -> 64 (R3,R9 spilled GBs); arg2=3 -> ~85 (R1=84); arg2=2 -> 128.
// Spill canary: FETCH_SIZE >> 100 MB with read:write >> 2:1.
// ======================= DURATION LAW (measured) ==========================
// R1/R4/R8/R10: dur/unit tracks VALU-pipe cycles ~1:1; occupancy 20-31%
// is irrelevant. The VALU pipe is the saturated resource. Optimize VALU
// CYCLES. v_pk_*_f32 (packed f32) = 2 f32/lane at scalar issue cost
// (this is where the 157.3 TF fp32 peak comes from) -> pair everything.
// =========================================================================

// packed fma helper: v2f32 llvm.fma -> V_PK_FMA_F32
__device__ __forceinline__ f32x2 fma2(f32x2 a, f32x2 b, f32x2 c) {
    return __builtin_elementwise_fma(a, b, c);
}
__device__ __forceinline__ f32x2 splat2(float x) { return (f32x2){x, x}; }

// inputs pre-scaled by log2(e): silu2(y) = y*sigmoid2(y) = log2e*silu(x);
// downstream weights carry ln2. Paired form: trans (exp2/rcp) stays
// scalar (no packed trans HW); the add/mul pair -> v_pk_add/v_pk_mul.
__device__ __forceinline__ f32x2 silu2x2(f32x2 y) {
    f32x2 e;
    e[0] = __builtin_amdgcn_exp2f(-y[0]);
    e[1] = __builtin_amdgcn_exp2f(-y[1]);
    f32x2 d = e + (f32x2){1.0f, 1.0f};     // v_pk_add_f32
    f32x2 r;
    r[0] = __builtin_amdgcn_rcpf(d[0]);
    r[1] = __builtin_amdgcn_rcpf(d[1]);
    return y * r;                           // v_pk_mul_f32
}

__device__ __forceinline__ float rdlane(float v, int l) {
    return __builtin_bit_cast(float, __builtin_amdgcn_readlane(__builtin_bit_cast(int, v), l));
}

// XOR-swizzled A-fragment LDS layout for 16x16x32 bf16 MFMA (verified):
// element (row,k) -> frag  = (k>>5)   [within a wave's 16-row region]
//                    slot  = ((row&15) ^ ((k>>5)&3) ^ (((k>>3)&3)<<2))
//                            + 16*((k>>3)&3)                             [16 B]
//                    byte  = (k&7)*2
// Reads: b128, 64 distinct slots, conflict-free. Writes: 2-way (free).
//
// STRUCTURE LOCKED TO THE R1 SHAPE (proven spill-free): ks-outer GEMM,
// A=H0 frags in regs, B=W1 frag read+consumed, acc[2][8] as MFMA C-chain
// only, epilogue strictly after. R5-R7 restructures all spilled; R9/R10
// W1-from-global needs >128 regs; both families closed.
//
// R11: packed-f32 rewrite of layer-0 / silu / epilogue-fma (pairs are
// natural: h=2l & 2l+1 twins; acc quad pairs). ~-11% VALU cycles.
// LDS: sW1 32 KB + sH0 16 KB = 48 KB -> 3 blocks/CU (LDS-capped, so
// (256,2)'s VGPR headroom costs no occupancy).

// Packed scatter accumulator: one f64 atomic carries sum + 65536*count.
#define CNT_UNIT 65536.0

__global__ __launch_bounds__(256, 2) void mlp_kernel(
    const float* __restrict__ v,    // [N,3] f32
    const float* __restrict__ rij,  // [E,3] f32
    const float* __restrict__ W0,   // [128,4]
    const float* __restrict__ b0,   // [128]
    const float* __restrict__ W1,   // [128,128] (n,k)
    const float* __restrict__ b1,   // [128]
    const float* __restrict__ W2,   // [128]
    const float* __restrict__ b2,   // [1]
    const int* __restrict__ eidx,   // [2,E] int32
    double* __restrict__ acc_i, double* __restrict__ acc_j,
    int E, int nchunks)             // chunk = 64 edges (4 waves x 16)
{
    __shared__ ushort_t sW1[16384];   // 32 KB, frag layout (unswizzled)
    __shared__ ushort_t sH0[8192];    // 16 KB, XOR-swizzled; wave w owns frags [4w,4w+4)

    const int tid  = threadIdx.x;
    const int lane = tid & 63;
    const int wave = tid >> 6;

    // ---- stage W1 (f32 -> bf16) into LDS (once per block) ----
    // W1's silu-prescale (log2e) cancels against h0' (ln2): staged UNSCALED.
    {
        int n = tid >> 1, half = tid & 1;
        const float* src = W1 + n * 128;
#pragma unroll
        for (int dk = 0; dk < 8; dk++) {
            int k0   = half * 64 + dk * 8;
            int frag = (n >> 4) * 4 + (k0 >> 5);
            int slot = (n & 15) + 16 * ((k0 >> 3) & 3);
            ushort_t tmp[8];
#pragma unroll
            for (int t = 0; t < 8; t++) tmp[t] = f2bf(src[k0 + t]);
            *(uint4*)(&sW1[frag * 512 + slot * 8]) = *(const uint4*)tmp;
        }
    }

    // ---- per-lane constants, PAIRED over h = {2*lane, 2*lane+1} ----
    f32x2 w0x, w0y, w0z, w0w, b0p;
    {
        int h0 = 2 * lane, h1 = 2 * lane + 1;
        w0x = (f32x2){W0[h0 * 4 + 0], W0[h1 * 4 + 0]} * splat2(LOG2E);
        w0y = (f32x2){W0[h0 * 4 + 1], W0[h1 * 4 + 1]} * splat2(LOG2E);
        w0z = (f32x2){W0[h0 * 4 + 2], W0[h1 * 4 + 2]} * splat2(LOG2E);
        w0w = (f32x2){W0[h0 * 4 + 3], W0[h1 * 4 + 3]} * splat2(LOG2E);
        b0p = (f32x2){b0[h0], b0[h1]} * splat2(LOG2E);
    }
    float b1v[8], w2v[8];
#pragma unroll
    for (int nt = 0; nt < 8; nt++) {
        int ccol = nt * 16 + (lane & 15);
        b1v[nt] = b1[ccol] * LOG2E;   // pre-activation scale for layer-1 silu2
        w2v[nt] = W2[ccol] * LN2;     // compensates log2e in silu2 output
    }
    const float b2f = b2[0];

    __syncthreads();   // sW1 ready; hot loop below is barrier-free

    const int q = lane >> 4, c = lane & 15, p = (lane >> 2) & 3, bsub = lane & 3;
    const int ple  = lane >> 2;     // edge-in-wave this lane preloads
    const int comp = lane & 3;      // 0..2: v component, 3: |r|/H

    // ---- gather preload for one chunk (lane-parallel) ----
    auto preload = [&](int ch, float& val_o, int& idx_o) {
        float val = 0.f; int idxr = 0;
        int pe = ch * 64 + wave * 16 + ple;
        if (ch < nchunks && pe < E) {
            if (comp == 3) {
                float r0 = rij[3 * pe], r1 = rij[3 * pe + 1], r2 = rij[3 * pe + 2];
                val = sqrtf(fmaf(r0, r0, fmaf(r1, r1, r2 * r2))) * (1.0f / 3.0f);
            } else {
                int i = eidx[pe], jj = eidx[E + pe];
                idxr = (comp == 1) ? jj : i;
                val = v[3 * i + comp] - v[3 * jj + comp];
            }
        }
        val_o = val; idx_o = idxr;
    };

    float val; int idxr;
    preload(blockIdx.x, val, idxr);   // prologue load for first chunk

    for (int chunk = blockIdx.x; chunk < nchunks; chunk += gridDim.x) {
        const float val_cur = val;
        const int   idx_cur = idxr;
        // issue next chunk's gathers now; consumed one full iteration later
        preload(chunk + (int)gridDim.x, val, idxr);

        const int ebase = chunk * 64 + wave * 16;

        // ===== two temporal halves: layer0 (packed) -> LDS -> H0 frags =====
        bf16x8 afr[2][4];
#pragma unroll
        for (int half = 0; half < 2; ++half) {
#pragma unroll
            for (int le = 0; le < 8; le++) {
                int se = half * 8 + le;
                float vx = rdlane(val_cur, se * 4 + 0);
                float vy = rdlane(val_cur, se * 4 + 1);
                float vz = rdlane(val_cur, se * 4 + 2);
                float rr = rdlane(val_cur, se * 4 + 3);
                // paired over (h=2l, h=2l+1): v_pk_fma chain
                f32x2 cc = fma2(w0x, splat2(rr), b0p);
                f32x2 dd = fma2(w0y, splat2(vx),
                           fma2(w0z, splat2(vy), w0w * splat2(vz)));
                f32x2 si = silu2x2(cc + dd);   // x_i: {h=2l, h=2l+1}
                f32x2 sj = silu2x2(cc - dd);   // x_j
                bf16x2 pki, pkj;
                pki[0] = (__bf16)si[0]; pki[1] = (__bf16)si[1];
                pkj[0] = (__bf16)sj[0]; pkj[1] = (__bf16)sj[1];
                int mi = 2 * le;                  // x_i row in [0,16); x_j row = mi+1
                int fr = wave * 4 + q;
                int sli = ((mi ^ q ^ (p << 2)) & 15) + (p << 4);
                int slj = (((mi + 1) ^ q ^ (p << 2)) & 15) + (p << 4);
                ((unsigned*)sH0)[fr * 256 + sli * 4 + bsub] = __builtin_bit_cast(unsigned, pki);
                ((unsigned*)sH0)[fr * 256 + slj * 4 + bsub] = __builtin_bit_cast(unsigned, pkj);
            }
            // cache this half's H0 fragments before half 1 overwrites the region
#pragma unroll
            for (int ks = 0; ks < 4; ks++) {
                int sl_rd = (((lane & 15) ^ ks ^ (q << 2)) & 15) + 16 * q;
                afr[half][ks] = *(const bf16x8*)(&sH0[(wave * 4 + ks) * 512 + sl_rd * 8]);
            }
        }

        // ===== GEMM: h1_pre' = H0' @ W1^T + b1' (R1-proven shape) =====
        f32x4 acc[2][8];
#pragma unroll
        for (int t = 0; t < 2; t++)
#pragma unroll
            for (int nt = 0; nt < 8; nt++)
                acc[t][nt] = (f32x4){b1v[nt], b1v[nt], b1v[nt], b1v[nt]};

#pragma unroll
        for (int ks = 0; ks < 4; ks++) {
#pragma unroll
            for (int nt = 0; nt < 8; nt++) {
                bf16x8 bb = *(const bf16x8*)(&sW1[(nt * 4 + ks) * 512 + lane * 8]);
                acc[0][nt] = __builtin_amdgcn_mfma_f32_16x16x32_bf16(afr[0][ks], bb, acc[0][nt], 0, 0, 0);
                acc[1][nt] = __builtin_amdgcn_mfma_f32_16x16x32_bf16(afr[1][ks], bb, acc[1][nt], 0, 0, 0);
            }
        }

        // ===== epilogue (packed): silu2(h1') . (W2*ln2) -> scatter-add =====
        f32x2 rs2[2][2] = {{{0.f, 0.f}, {0.f, 0.f}}, {{0.f, 0.f}, {0.f, 0.f}}};
#pragma unroll
        for (int t = 0; t < 2; t++)
#pragma unroll
            for (int nt = 0; nt < 8; nt++) {
                f32x2 w2s = splat2(w2v[nt]);
                f32x2 xa = {acc[t][nt][0], acc[t][nt][1]};   // b1' folded in init
                f32x2 xb = {acc[t][nt][2], acc[t][nt][3]};
                rs2[t][0] = fma2(silu2x2(xa), w2s, rs2[t][0]);
                rs2[t][1] = fma2(silu2x2(xb), w2s, rs2[t][1]);
            }
#pragma unroll
        for (int t = 0; t < 2; t++)
#pragma unroll
            for (int r = 0; r < 4; r++) {
                float s = rs2[t][r >> 1][r & 1];
                s += __shfl_xor(s, 1, 64);
                s += __shfl_xor(s, 2, 64);
                s += __shfl_xor(s, 4, 64);
                s += __shfl_xor(s, 8, 64);
                int el  = t * 8 + q * 2 + (r >> 1);        // edge within wave's 16
                int src = el * 4 + (r & 1);                // comp0 lane holds i, comp1 holds j
                int node = __shfl(idx_cur, src, 64);
                int e = ebase + el;
                if (c == 0 && e < E) {
                    double contrib = (double)(s + b2f) + CNT_UNIT;
                    if (r & 1) atomicAdd(&acc_j[node], contrib);
                    else       atomicAdd(&acc_i[node], contrib);
                }
            }
        // wave-local LDS WAR across chunks is safe: one wave's DS ops are in-order.
    }
}

__global__ void finalize_kernel(const double* __restrict__ acc_i,
                                const double* __restrict__ acc_j,
                                float* __restrict__ out, int N)
{
    int n = blockIdx.x * 256 + threadIdx.x;
    if (n < N) {
        double ti = acc_i[n], tj = acc_j[n];
        double ci = rint(ti * (1.0 / CNT_UNIT));
        double cj = rint(tj * (1.0 / CNT_UNIT));
        double si = ti - ci * CNT_UNIT;
        double sj = tj - cj * CNT_UNIT;
        out[n] = (float)(si / fmax(ci, 1.0) + sj / fmax(cj, 1.0));
    }
}

extern "C" void kernel_launch(void* const* d_in, const int* in_sizes, int n_in,
                              void* d_out, int out_size, void* d_ws, size_t ws_size,
                              hipStream_t stream) {
    const float* v   = (const float*)d_in[0];
    const float* rij = (const float*)d_in[1];
    const float* W0  = (const float*)d_in[2];
    const float* b0  = (const float*)d_in[3];
    const float* W1  = (const float*)d_in[4];
    const float* b1  = (const float*)d_in[5];
    const float* W2  = (const float*)d_in[6];
    const float* b2  = (const float*)d_in[7];
    const int* eidx  = (const int*)d_in[8];

    const int E = in_sizes[1] / 3;
    const int N = out_size;

    double* acc_i = (double*)d_ws;
    double* acc_j = acc_i + N;

    hipMemsetAsync(d_ws, 0, (size_t)2 * N * sizeof(double), stream);

    int nchunks = (E + 63) / 64;
    int grid = nchunks < 768 ? nchunks : 768;
    mlp_kernel<<<grid, 256, 0, stream>>>(v, rij, W0, b0, W1, b1, W2, b2, eidx,
                                         acc_i, acc_j, E, nchunks);
    finalize_kernel<<<(N + 255) / 256, 256, 0, stream>>>(acc_i, acc_j,
                                                         (float*)d_out, N);
}

// Round 12
// 378.403 us; speedup vs baseline: 3.4789x; 1.0808x over previous
//
#include <hip/hip_runtime.h>

typedef unsigned short ushort_t;
typedef __bf16 bf16x8 __attribute__((ext_vector_type(8)));
typedef __bf16 bf16x2 __attribute__((ext_vector_type(2)));
typedef float f32x4 __attribute__((ext_vector_type(4)));

#define LOG2E 1.4426950408889634f
#define LN2   0.6931471805599453f

__device__ __forceinline__ ushort_t f2bf(float f) {
    unsigned u;
    __builtin_memcpy(&u, &f, 4);
    u += 0x7fffu + ((u >> 16) & 1u);   // RNE
    return (ushort_t)(u >> 16);
}

// ===================== SESSION LAWS (measured R1-R11) =====================
// 1) LAUNCH BOUNDS: __launch_bounds__(B, arg2) caps VGPR at 256/arg2,
//    independent of B (arg2=4 -> 64; =3 -> ~85; =2 -> 128). Spill canary:
//    FETCH_SIZE >> 100 MB with read:write >> 2:1 (R3/R5/R6/R7/R9/R10).
// 2) DURATION ~ VALU lane-work. Occupancy 19-31% irrelevant (R4/R8/R11).
// 3) v_pk_*_f32 is NOT double-rate on CDNA4 (157.3 TF = scalar rate);
//    packing f32 compresses instructions, not lane-cycles -> R11 -10%.
// 4) Trans pipe ~25% utilized; batching rcp costs more VALU than it saves
//    (R4). Readlane->LDS broadcast swap is neutral (R8).
// 5) Structure below (R1 shape) is the proven optimum: ks-outer GEMM,
//    A=H0 frags in regs, B=W1 read+consumed, acc as MFMA C-chain only,
//    epilogue strictly after GEMM. All restructures spilled or regressed.
// =========================================================================
//
// R12 = R1 byte-exact + s_setprio(1) around the MFMA cluster. Hot loop is
// barrier-free -> resident waves sit at different phases; boosting the
// MFMA-issuing wave is the measured-positive regime for setprio (guide
// m191: +4-7% attn; hurts only barrier-lockstep kernels, m190).

__device__ __forceinline__ float silu2(float y) {
    // inputs pre-scaled by log2(e): silu2(y) = log2e*silu(x); W2 carries ln2.
    float e = __builtin_amdgcn_exp2f(-y);
    return y * __builtin_amdgcn_rcpf(1.0f + e);
}

__device__ __forceinline__ float rdlane(float v, int l) {
    return __builtin_bit_cast(float, __builtin_amdgcn_readlane(__builtin_bit_cast(int, v), l));
}

// XOR-swizzled A-fragment LDS layout for 16x16x32 bf16 MFMA (verified):
// element (row,k) -> frag  = (k>>5)   [within a wave's 16-row region]
//                    slot  = ((row&15) ^ ((k>>5)&3) ^ (((k>>3)&3)<<2))
//                            + 16*((k>>3)&3)                             [16 B]
//                    byte  = (k&7)*2
// Reads: b128, 64 distinct slots, conflict-free. Writes: 2-way (free).
//
// LDS: sW1 32 KB + sH0 16 KB = 48 KB -> 3 blocks/CU (12 waves/CU).
// Hot loop barrier-free: wave owns frags [4w,4w+4) of sH0; wave-local DS
// ops are in-order (WAR across chunk halves is safe).

// Packed scatter accumulator: one f64 atomic carries sum + 65536*count.
#define CNT_UNIT 65536.0

__global__ __launch_bounds__(256, 3) void mlp_kernel(
    const float* __restrict__ v,    // [N,3] f32
    const float* __restrict__ rij,  // [E,3] f32
    const float* __restrict__ W0,   // [128,4]
    const float* __restrict__ b0,   // [128]
    const float* __restrict__ W1,   // [128,128] (n,k)
    const float* __restrict__ b1,   // [128]
    const float* __restrict__ W2,   // [128]
    const float* __restrict__ b2,   // [1]
    const int* __restrict__ eidx,   // [2,E] int32
    double* __restrict__ acc_i, double* __restrict__ acc_j,
    int E, int nchunks)             // chunk = 64 edges (4 waves x 16)
{
    __shared__ ushort_t sW1[16384];   // 32 KB, frag layout (unswizzled)
    __shared__ ushort_t sH0[8192];    // 16 KB, XOR-swizzled; wave w owns frags [4w,4w+4)

    const int tid  = threadIdx.x;
    const int lane = tid & 63;
    const int wave = tid >> 6;

    // ---- stage W1 (f32 -> bf16) into LDS (once per block) ----
    // W1's silu-prescale (log2e) cancels against h0' (ln2): staged UNSCALED.
    {
        int n = tid >> 1, half = tid & 1;
        const float* src = W1 + n * 128;
#pragma unroll
        for (int dk = 0; dk < 8; dk++) {
            int k0   = half * 64 + dk * 8;
            int frag = (n >> 4) * 4 + (k0 >> 5);
            int slot = (n & 15) + 16 * ((k0 >> 3) & 3);
            ushort_t tmp[8];
#pragma unroll
            for (int t = 0; t < 8; t++) tmp[t] = f2bf(src[k0 + t]);
            *(uint4*)(&sW1[frag * 512 + slot * 8]) = *(const uint4*)tmp;
        }
    }

    // ---- per-lane constants (log2e/ln2 folded) ----
    float4 w0q[2]; float b0v[2];
#pragma unroll
    for (int kk = 0; kk < 2; kk++) {
        int h = 2 * lane + kk;
        w0q[kk].x = W0[h * 4 + 0] * LOG2E;
        w0q[kk].y = W0[h * 4 + 1] * LOG2E;
        w0q[kk].z = W0[h * 4 + 2] * LOG2E;
        w0q[kk].w = W0[h * 4 + 3] * LOG2E;
        b0v[kk]   = b0[h] * LOG2E;
    }
    float b1v[8], w2v[8];
#pragma unroll
    for (int nt = 0; nt < 8; nt++) {
        int ccol = nt * 16 + (lane & 15);
        b1v[nt] = b1[ccol] * LOG2E;   // pre-activation scale for layer-1 silu2
        w2v[nt] = W2[ccol] * LN2;     // compensates log2e in silu2 output
    }
    const float b2f = b2[0];

    __syncthreads();   // sW1 ready; hot loop below is barrier-free

    const int q = lane >> 4, c = lane & 15, p = (lane >> 2) & 3, bsub = lane & 3;
    const int ple  = lane >> 2;     // edge-in-wave this lane preloads
    const int comp = lane & 3;      // 0..2: v component, 3: |r|/H

    // ---- gather preload for one chunk (lane-parallel) ----
    auto preload = [&](int ch, float& val_o, int& idx_o) {
        float val = 0.f; int idxr = 0;
        int pe = ch * 64 + wave * 16 + ple;
        if (ch < nchunks && pe < E) {
            if (comp == 3) {
                float r0 = rij[3 * pe], r1 = rij[3 * pe + 1], r2 = rij[3 * pe + 2];
                val = sqrtf(fmaf(r0, r0, fmaf(r1, r1, r2 * r2))) * (1.0f / 3.0f);
            } else {
                int i = eidx[pe], jj = eidx[E + pe];
                idxr = (comp == 1) ? jj : i;
                val = v[3 * i + comp] - v[3 * jj + comp];
            }
        }
        val_o = val; idx_o = idxr;
    };

    float val; int idxr;
    preload(blockIdx.x, val, idxr);   // prologue load for first chunk

    for (int chunk = blockIdx.x; chunk < nchunks; chunk += gridDim.x) {
        const float val_cur = val;
        const int   idx_cur = idxr;
        // issue next chunk's gathers now; consumed one full iteration later
        preload(chunk + (int)gridDim.x, val, idxr);

        const int ebase = chunk * 64 + wave * 16;

        // ===== two temporal halves: layer0 -> 16-row LDS region -> H0 frags =====
        bf16x8 afr[2][4];
#pragma unroll
        for (int half = 0; half < 2; ++half) {
#pragma unroll
            for (int le = 0; le < 8; le++) {
                int se = half * 8 + le;
                float vx = rdlane(val_cur, se * 4 + 0);
                float vy = rdlane(val_cur, se * 4 + 1);
                float vz = rdlane(val_cur, se * 4 + 2);
                float rr = rdlane(val_cur, se * 4 + 3);
                float cc0 = fmaf(w0q[0].x, rr, b0v[0]);
                float dd0 = fmaf(w0q[0].y, vx, fmaf(w0q[0].z, vy, w0q[0].w * vz));
                float cc1 = fmaf(w0q[1].x, rr, b0v[1]);
                float dd1 = fmaf(w0q[1].y, vx, fmaf(w0q[1].z, vy, w0q[1].w * vz));
                float s0 = silu2(cc0 + dd0);   // x_i, h=2l
                float s1 = silu2(cc0 - dd0);   // x_j, h=2l
                float s2 = silu2(cc1 + dd1);   // x_i, h=2l+1
                float s3 = silu2(cc1 - dd1);   // x_j, h=2l+1
                bf16x2 pki, pkj;
                pki[0] = (__bf16)s0; pki[1] = (__bf16)s2;
                pkj[0] = (__bf16)s1; pkj[1] = (__bf16)s3;
                int mi = 2 * le;                  // x_i row in [0,16); x_j row = mi+1
                int fr = wave * 4 + q;
                int sli = ((mi ^ q ^ (p << 2)) & 15) + (p << 4);
                int slj = (((mi + 1) ^ q ^ (p << 2)) & 15) + (p << 4);
                ((unsigned*)sH0)[fr * 256 + sli * 4 + bsub] = __builtin_bit_cast(unsigned, pki);
                ((unsigned*)sH0)[fr * 256 + slj * 4 + bsub] = __builtin_bit_cast(unsigned, pkj);
            }
            // cache this half's H0 fragments before half 1 overwrites the region
#pragma unroll
            for (int ks = 0; ks < 4; ks++) {
                int sl_rd = (((lane & 15) ^ ks ^ (q << 2)) & 15) + 16 * q;
                afr[half][ks] = *(const bf16x8*)(&sH0[(wave * 4 + ks) * 512 + sl_rd * 8]);
            }
        }

        // ===== GEMM: h1_pre' = H0' @ W1^T + b1' (R1-proven shape) =====
        f32x4 acc[2][8];
#pragma unroll
        for (int t = 0; t < 2; t++)
#pragma unroll
            for (int nt = 0; nt < 8; nt++)
                acc[t][nt] = (f32x4){b1v[nt], b1v[nt], b1v[nt], b1v[nt]};

        // setprio(1): waves are phase-staggered (no barriers); prioritize
        // the wave occupying the matrix pipe (measured-positive regime).
        __builtin_amdgcn_s_setprio(1);
#pragma unroll
        for (int ks = 0; ks < 4; ks++) {
#pragma unroll
            for (int nt = 0; nt < 8; nt++) {
                bf16x8 bb = *(const bf16x8*)(&sW1[(nt * 4 + ks) * 512 + lane * 8]);
                acc[0][nt] = __builtin_amdgcn_mfma_f32_16x16x32_bf16(afr[0][ks], bb, acc[0][nt], 0, 0, 0);
                acc[1][nt] = __builtin_amdgcn_mfma_f32_16x16x32_bf16(afr[1][ks], bb, acc[1][nt], 0, 0, 0);
            }
        }
        __builtin_amdgcn_s_setprio(0);

        // ===== epilogue: silu2(h1') . (W2*ln2) -> +b2 -> packed f64 scatter-add =====
        float rs[2][4] = {{0.f, 0.f, 0.f, 0.f}, {0.f, 0.f, 0.f, 0.f}};
#pragma unroll
        for (int t = 0; t < 2; t++)
#pragma unroll
            for (int nt = 0; nt < 8; nt++)
#pragma unroll
                for (int r = 0; r < 4; r++) {
                    float x = acc[t][nt][r];          // b1' folded into acc init
                    rs[t][r] = fmaf(silu2(x), w2v[nt], rs[t][r]);
                }
#pragma unroll
        for (int t = 0; t < 2; t++)
#pragma unroll
            for (int r = 0; r < 4; r++) {
                float s = rs[t][r];
                s += __shfl_xor(s, 1, 64);
                s += __shfl_xor(s, 2, 64);
                s += __shfl_xor(s, 4, 64);
                s += __shfl_xor(s, 8, 64);
                int el  = t * 8 + q * 2 + (r >> 1);        // edge within wave's 16
                int src = el * 4 + (r & 1);                // comp0 lane holds i, comp1 holds j
                int node = __shfl(idx_cur, src, 64);
                int e = ebase + el;
                if (c == 0 && e < E) {
                    double contrib = (double)(s + b2f) + CNT_UNIT;
                    if (r & 1) atomicAdd(&acc_j[node], contrib);
                    else       atomicAdd(&acc_i[node], contrib);
                }
            }
        // wave-local LDS WAR across chunks is safe: one wave's DS ops are in-order.
    }
}

__global__ void finalize_kernel(const double* __restrict__ acc_i,
                                const double* __restrict__ acc_j,
                                float* __restrict__ out, int N)
{
    int n = blockIdx.x * 256 + threadIdx.x;
    if (n < N) {
        double ti = acc_i[n], tj = acc_j[n];
        double ci = rint(ti * (1.0 / CNT_UNIT));
        double cj = rint(tj * (1.0 / CNT_UNIT));
        double si = ti - ci * CNT_UNIT;
        double sj = tj - cj * CNT_UNIT;
        out[n] = (float)(si / fmax(ci, 1.0) + sj / fmax(cj, 1.0));
    }
}

extern "C" void kernel_launch(void* const* d_in, const int* in_sizes, int n_in,
                              void* d_out, int out_size, void* d_ws, size_t ws_size,
                              hipStream_t stream) {
    const float* v   = (const float*)d_in[0];
    const float* rij = (const float*)d_in[1];
    const float* W0  = (const float*)d_in[2];
    const float* b0  = (const float*)d_in[3];
    const float* W1  = (const float*)d_in[4];
    const float* b1  = (const float*)d_in[5];
    const float* W2  = (const float*)d_in[6];
    const float* b2  = (const float*)d_in[7];
    const int* eidx  = (const int*)d_in[8];

    const int E = in_sizes[1] / 3;
    const int N = out_size;

    double* acc_i = (double*)d_ws;
    double* acc_j = acc_i + N;

    hipMemsetAsync(d_ws, 0, (size_t)2 * N * sizeof(double), stream);

    int nchunks = (E + 63) / 64;
    int grid = nchunks < 768 ? nchunks : 768;
    mlp_kernel<<<grid, 256, 0, stream>>>(v, rij, W0, b0, W1, b1, W2, b2, eidx,
                                         acc_i, acc_j, E, nchunks);
    finalize_kernel<<<(N + 255) / 256, 256, 0, stream>>>(acc_i, acc_j,
                                                         (float*)d_out, N);
}